// Round 3
// baseline (1002.105 us; speedup 1.0000x reference)
//
#include <hip/hip_runtime.h>
#include <hip/hip_bf16.h>

// LSTM encoder, single fused kernel (producer/consumer).
//   Grid = 256 WGs x 256 thr. WGs 0-63: persistent recurrence, one batch row
//   each. WGs 64-255: xg producers, 8 timesteps per chunk (256 chunks),
//   publishing via agent-scope release flags in d_ws.
// Consumer (R3): 4 waves; lane pair splits GATES (gh=0 -> {i,g}, gh=1 ->
//   {f,o}), full K per lane, 64 sdot4 in 8 independent 8-deep chains.
//   NO s_barrier in the step loop: h exchange via LDS seqlock. Writer wave
//   stores its 32 h-bytes then RELEASE-stores seq[wv]=n (lgkm drain orders
//   bytes before seq). Reader issues ONE asm batch: ds_read_b128 of seq[0..3]
//   FIRST, then 8 ds_read_b128 of h, single lgkmcnt(0); accepts iff all
//   seq>=n (DS requests of a wave are serviced in issue order, so seq>=n
//   implies the h reads were serviced after the writer's h-bytes). Retry
//   re-issues the batch; monotonic >= compare makes +-1-step wave drift
//   deadlock-free and absorbs arrival skew.
//   Gate-q1 dots run before gate-q0 so sigma(g1) hides under dot issue; only
//   sigma(g0)+tanh are exposed on the spine. Quant uses fused magic-add
//   fma(so*127, t2, 1.5*2^23). Chunk-flag prefetch at s==2, check+acquire
//   fence at s==6 (prefetch burst ~6 substeps old -> vmcnt(0) nearly free).
// Fallback single kernel if ws_size too small.

namespace {

constexpr int T_LEN  = 2048;
constexpr int Bsz    = 64;
constexpr int Dd     = 128;
constexpr int Hh     = 128;
constexpr int Gg     = 512;
constexpr int XS     = 136;    // bf16 LDS row stride (producer A-tile / fallback)
constexpr int NCHUNK = 256;    // 8 timesteps per chunk
constexpr int CONS   = 64;     // consumer WGs (one per batch row)
constexpr int PROD   = 192;    // producer WGs
constexpr unsigned int SENT = 0x5EC7C0DEu;

typedef __attribute__((ext_vector_type(8))) short   short8;
typedef __attribute__((ext_vector_type(4))) float   floatx4;
typedef __attribute__((ext_vector_type(4))) int     intx4;
typedef __attribute__((ext_vector_type(2))) unsigned int uintx2;

#define MFMA16(a, b, c) __builtin_amdgcn_mfma_f32_16x16x32_bf16((a), (b), (c), 0, 0, 0)

#if __has_builtin(__builtin_amdgcn_sdot4)
__device__ __forceinline__ int dot4i8(int a, int b, int c) {
    return __builtin_amdgcn_sdot4(a, b, c, false);
}
#else
__device__ __forceinline__ int dot4i8(int a, int b, int c) {
#pragma unroll
    for (int j = 0; j < 4; ++j)
        c += ((a << (24 - 8 * j)) >> 24) * ((b << (24 - 8 * j)) >> 24);
    return c;
}
#endif

// value from partner lane^1 (quad_perm [1,0,3,2]) -- full-rate VALU
__device__ __forceinline__ int xor1_i(int v) {
    return __builtin_amdgcn_mov_dpp(v, 0xB1, 0xF, 0xF, true);
}

__device__ __forceinline__ float sigmoidf_(float x) {
    return __builtin_amdgcn_rcpf(1.0f + __builtin_amdgcn_exp2f(x * -1.44269504f));
}
__device__ __forceinline__ float tanhf_(float x) {
    return __builtin_fmaf(-2.0f,
        __builtin_amdgcn_rcpf(1.0f + __builtin_amdgcn_exp2f(x * 2.88539008f)), 1.0f);
}
__device__ __forceinline__ unsigned short f2bf(float f) {
    __hip_bfloat16 h = __float2bfloat16(f);  // RNE
    union { __hip_bfloat16 b; unsigned short u; } v; v.b = h; return v.u;
}
__device__ __forceinline__ float fi_(unsigned int u) {
    union { unsigned int u; float f; } v; v.u = u; return v.f;
}
__device__ __forceinline__ int f_as_i(float f) {
    union { float f; int i; } v; v.f = f; return v.i;
}
__device__ __forceinline__ float i_as_f(int i) {
    union { int i; float f; } v; v.i = i; return v.f;
}
__device__ __forceinline__ uintx2 f4bf(const float4 v) {
    union { unsigned short us[4]; uintx2 u2; } p;
    p.us[0] = f2bf(v.x); p.us[1] = f2bf(v.y); p.us[2] = f2bf(v.z); p.us[3] = f2bf(v.w);
    return p.u2;
}
__device__ __forceinline__ short8 ld8bf(const float* p) {
    const float4 a = *reinterpret_cast<const float4*>(p);
    const float4 b = *reinterpret_cast<const float4*>(p + 4);
    short8 s;
    s[0] = (short)f2bf(a.x); s[1] = (short)f2bf(a.y);
    s[2] = (short)f2bf(a.z); s[3] = (short)f2bf(a.w);
    s[4] = (short)f2bf(b.x); s[5] = (short)f2bf(b.y);
    s[6] = (short)f2bf(b.z); s[7] = (short)f2bf(b.w);
    return s;
}
__device__ __forceinline__ void wait_chunk(const unsigned int* flags, int k) {
    while (__hip_atomic_load(&flags[k], __ATOMIC_RELAXED,
                             __HIP_MEMORY_SCOPE_AGENT) != SENT)
        __builtin_amdgcn_s_sleep(2);
    __builtin_amdgcn_fence(__ATOMIC_ACQUIRE, "agent");
}

// =================== fused producer/consumer kernel ==========================
__global__ __launch_bounds__(256) void lstm_fused_all(
    const int*   __restrict__ tokens,
    const float* __restrict__ emb,
    const float* __restrict__ Wih,
    const float* __restrict__ Whh,
    const float* __restrict__ bih,
    const float* __restrict__ bhh,
    unsigned short* __restrict__ xg,     // [T][64][128][4] bf16, in d_ws
    unsigned int*   __restrict__ flags,  // [NCHUNK], in d_ws after xg
    float*       __restrict__ out)       // [2][64][128] fp32
{
    __shared__ __align__(16) unsigned short albs[2][64 * XS];  // producer A-tile

    const int tid = threadIdx.x;

    if (blockIdx.x < CONS) {
        // ================= CONSUMER: one batch row ===========================
        // LDS map (albs is the only __shared__ -> LDS offset 0):
        //   bytes [0..255]   : h ping-pong, [2 parity][128] i8
        //   bytes [256..271] : seq[4] (per-wave step counters)
        signed char (*hbuf)[128] =
            reinterpret_cast<signed char (*)[128]>(&albs[0][0]);  // [2][128]
        int* seqP = reinterpret_cast<int*>(
            reinterpret_cast<char*>(&albs[0][0]) + 256);

        const int wv = tid >> 6;          // wave 0..3
        const int l  = tid & 63;
        const int gh = l & 1;             // gate-half: 0 -> {i,g}, 1 -> {f,o}
        const int c  = wv * 32 + (l >> 1);  // hidden column
        const int b  = blockIdx.x;        // batch row

        // per-lane activation constants (see tail): gh0 computes tanh via
        // 2*sigmoid(2x)-1; gh1 computes a plain sigmoid.
        const float kf = gh ? 1.0f : 2.0f;     // input scale AND output scale
        const float kb = gh ? 0.0f : -1.0f;    // output offset
        const int   sh = gh ? 0 : 16;          // bf16 unpack shift for xg

        // Whh rows for this lane's two gates {gh, 2+gh}, full K -> i8
        int   wq[2][32];
        float dq[2];
#pragma unroll
        for (int q = 0; q < 2; ++q) {
            const int g = q * 2 + gh;
            const float* wr = Whh + (size_t)(g * 128 + c) * Hh;
            float am = 0.f;
#pragma unroll 8
            for (int k = 0; k < 128; k += 4) {
                const float4 v = *reinterpret_cast<const float4*>(wr + k);
                am = fmaxf(am, fmaxf(fmaxf(fabsf(v.x), fabsf(v.y)),
                                     fmaxf(fabsf(v.z), fabsf(v.w))));
            }
            const float swm = fmaxf(am, 1e-20f);
            dq[q] = swm * (1.0f / (127.0f * 127.0f));
            const float inv = 127.0f / swm;
#pragma unroll
            for (int d = 0; d < 32; ++d) {
                const float4 v = *reinterpret_cast<const float4*>(wr + d * 4);
                const int b0 = (int)__builtin_rintf(v.x * inv);
                const int b1 = (int)__builtin_rintf(v.y * inv);
                const int b2 = (int)__builtin_rintf(v.z * inv);
                const int b3 = (int)__builtin_rintf(v.w * inv);
                wq[q][d] = (b0 & 0xff) | ((b1 & 0xff) << 8) |
                           ((b2 & 0xff) << 16) | ((b3 & 0xff) << 24);
            }
        }

        // init seq counters to -1 (pre-step-0), once; single barrier
        if (tid < 4) seqP[tid] = -1;
        __syncthreads();

        // h(0) = 0 in regs (buffers always written before read); full K
        intx4 hv[8];
#pragma unroll
        for (int j = 0; j < 8; ++j) hv[j] = (intx4){0, 0, 0, 0};

        const unsigned short* xptr = xg + (size_t)b * Gg + c * 4;
        const size_t xstride = (size_t)Bsz * Gg;

        // startup: verify chunks 0 and 1; load chunk 0
        wait_chunk(flags, 0);
        uintx2 xc[8], xcn[8];
#pragma unroll
        for (int u = 0; u < 8; ++u)
            xc[u] = *reinterpret_cast<const uintx2*>(xptr + (size_t)u * xstride);
        wait_chunk(flags, 1);

        float c_state = 0.0f;
        float h_last  = 0.0f;
        unsigned int fpre = SENT;

        for (int g = 0; g < NCHUNK; ++g) {
#pragma unroll
            for (int s = 0; s < 8; ++s) {
                const int n = (g << 3) + s;   // global step index
                if (s == 0) {
                    // flag[g+1] verified a chunk ago -> load immediately
                    int tn = g + 1;
                    if (tn >= NCHUNK) tn = 0;       // dummy re-load of chunk 0
                    const size_t tb = (size_t)tn * 8;
#pragma unroll
                    for (int u = 0; u < 8; ++u)
                        xcn[u] = *reinterpret_cast<const uintx2*>(
                            xptr + (tb + u) * xstride);
                }
                if (s == 2) {
                    // prefetch the distance-2 flag (hide L2 latency)
                    if (g + 2 < NCHUNK)
                        fpre = __hip_atomic_load(&flags[g + 2], __ATOMIC_RELAXED,
                                                 __HIP_MEMORY_SCOPE_AGENT);
                }
                if (s == 6) {
                    // distance-2 flag check; acquire fence here -- the s==0
                    // prefetch burst is ~6 substeps old, so vmcnt(0) is cheap
                    if (g + 2 < NCHUNK) {
                        if (fpre != SENT) wait_chunk(flags, g + 2);
                        else __builtin_amdgcn_fence(__ATOMIC_ACQUIRE, "agent");
                    }
                }

                // gate q1 ({g,o}) dots FIRST so sigma(g1) hides under the
                // gate q0 dot issue; q0 ({i,f}) second.
                int b0 = 0, b1 = 0, b2 = 0, b3 = 0;
#pragma unroll
                for (int j = 0; j < 8; ++j) {
                    const intx4 h4 = hv[j];
                    b0 = dot4i8(wq[1][j * 4 + 0], h4[0], b0);
                    b1 = dot4i8(wq[1][j * 4 + 1], h4[1], b1);
                    b2 = dot4i8(wq[1][j * 4 + 2], h4[2], b2);
                    b3 = dot4i8(wq[1][j * 4 + 3], h4[3], b3);
                }
                const int m1 = (b0 + b1) + (b2 + b3);

                const uintx2 xv = xc[s];
                const float x1 = fi_((xv.y << sh) & 0xffff0000u);  // g or o
                const float g1 = (float)m1 * dq[1] + x1;
                const float r2 = sigmoidf_(g1 * kf);      // sig(2gv) / so
                const float v2 = __builtin_fmaf(r2, kf, kb);  // tg / so
                const float so127 = v2 * 127.0f;          // gh1: so*127

                int a0 = 0, a1 = 0, a2 = 0, a3 = 0;
#pragma unroll
                for (int j = 0; j < 8; ++j) {
                    const intx4 h4 = hv[j];
                    a0 = dot4i8(wq[0][j * 4 + 0], h4[0], a0);
                    a1 = dot4i8(wq[0][j * 4 + 1], h4[1], a1);
                    a2 = dot4i8(wq[0][j * 4 + 2], h4[2], a2);
                    a3 = dot4i8(wq[0][j * 4 + 3], h4[3], a3);
                }
                const int m0 = (a0 + a1) + (a2 + a3);

                const float x0 = fi_((xv.x << sh) & 0xffff0000u);  // i or f
                const float g0 = (float)m0 * dq[0] + x0;
                const float r1 = sigmoidf_(g0);           // si (gh0) / sf (gh1)
                const float A  = r1 * v2;                 // si*tg / (unused)
                // one DPP swap: gh0 sends A, receives sf; gh1 sends sf, recv A
                const float swv = i_as_f(xor1_i(f_as_i(gh ? r1 : A)));
                const float F   = gh ? r1 : swv;          // sf on both lanes
                const float Ag  = gh ? swv : A;           // si*tg on both lanes
                c_state = __builtin_fmaf(F, c_state, Ag);
                const float t2 = tanhf_(c_state);
                h_last = v2 * t2;                         // valid on gh1: so*t2

                const int nxt = (s & 1) ^ 1;        // buffer parity of t+1
                if (gh == 1) {
                    // fused quant: round(so*127 * t2) via magic-add FMA (RNE)
                    const int q =
                        f_as_i(__builtin_fmaf(so127, t2, 12582912.0f));
                    hbuf[nxt][c] = (signed char)(q & 0xff);
                }
                // release: this wave's h bytes retire before seq[wv]=n lands
                if (l == 1)
                    __hip_atomic_store(&seqP[wv], n, __ATOMIC_RELEASE,
                                       __HIP_MEMORY_SCOPE_WORKGROUP);
                if (s == 7) {
#pragma unroll
                    for (int u = 0; u < 8; ++u) xc[u] = xcn[u];
                }

                // optimistic seqlock read of h(n): seq FIRST, then data, one
                // lgkmcnt(0). DS requests of a wave are serviced in issue
                // order, so seq>=n proves data reads saw the writer's bytes.
                {
                    const unsigned hoff = (unsigned)(nxt << 7);
                    intx4 s4;
                    do {
                        asm volatile(
                            "ds_read_b128 %0, %9 offset:256\n\t"
                            "ds_read_b128 %1, %10\n\t"
                            "ds_read_b128 %2, %10 offset:16\n\t"
                            "ds_read_b128 %3, %10 offset:32\n\t"
                            "ds_read_b128 %4, %10 offset:48\n\t"
                            "ds_read_b128 %5, %10 offset:64\n\t"
                            "ds_read_b128 %6, %10 offset:80\n\t"
                            "ds_read_b128 %7, %10 offset:96\n\t"
                            "ds_read_b128 %8, %10 offset:112\n\t"
                            "s_waitcnt lgkmcnt(0)"
                            : "=&v"(s4), "=&v"(hv[0]), "=&v"(hv[1]),
                              "=&v"(hv[2]), "=&v"(hv[3]), "=&v"(hv[4]),
                              "=&v"(hv[5]), "=&v"(hv[6]), "=&v"(hv[7])
                            : "v"(0u), "v"(hoff)
                            : "memory");
                    } while (s4[0] < n || s4[1] < n || s4[2] < n || s4[3] < n);
                }
            }
        }

        if (gh == 1) {
            out[b * Hh + c]            = h_last;
            out[Bsz * Hh + b * Hh + c] = c_state;
        }
    } else {
        // ================= PRODUCER: xg chunks of 8 timesteps ================
        const int pid  = blockIdx.x - CONS;
        const int wv   = tid >> 6;
        const int l    = tid & 63;
        const int quad = l >> 4;
        const int cl   = l & 15;
        const int srow = tid >> 2, sseg = tid & 3;   // staging: row, 32-col seg

        // bias for this lane's two hh columns (j = wv*2 + jj)
        float bias[2][4];
#pragma unroll
        for (int jj = 0; jj < 2; ++jj) {
            const int hhj = (wv * 2 + jj) * 16 + cl;
#pragma unroll
            for (int g = 0; g < 4; ++g)
                bias[jj][g] = bih[g * 128 + hhj] + bhh[g * 128 + hhj];
        }

        for (int chunk = pid; chunk < NCHUNK; chunk += PROD) {
            const int t0 = chunk * 8;

            {   // stage t0 into buf 0
                const int tok = tokens[srow * T_LEN + t0];
                const float* src = emb + (size_t)tok * Dd + sseg * 32;
#pragma unroll
                for (int p = 0; p < 4; ++p)
                    *reinterpret_cast<short8*>(
                        &albs[0][srow * XS + sseg * 32 + p * 8]) = ld8bf(src + p * 8);
            }
            __syncthreads();

            for (int tt = 0; tt < 8; ++tt) {
                const int cur = tt & 1, nxt = cur ^ 1;
                if (tt < 7) {   // stage next t
                    const int tok = tokens[srow * T_LEN + t0 + tt + 1];
                    const float* src = emb + (size_t)tok * Dd + sseg * 32;
#pragma unroll
                    for (int p = 0; p < 4; ++p)
                        *reinterpret_cast<short8*>(
                            &albs[nxt][srow * XS + sseg * 32 + p * 8]) =
                            ld8bf(src + p * 8);
                }

                // A-fragments for all 4 m-tiles x 4 k-chunks
                short8 af[4][4];
#pragma unroll
                for (int m = 0; m < 4; ++m)
#pragma unroll
                    for (int k = 0; k < 4; ++k)
                        af[m][k] = *reinterpret_cast<const short8*>(
                            &albs[cur][(m * 16 + cl) * XS + k * 32 + quad * 8]);

                const int t = t0 + tt;
#pragma unroll
                for (int jj = 0; jj < 2; ++jj) {
                    const int hhj = (wv * 2 + jj) * 16 + cl;
                    floatx4 acc[4][4];  // [g][m]
#pragma unroll
                    for (int g = 0; g < 4; ++g)
#pragma unroll
                        for (int m = 0; m < 4; ++m)
                            acc[g][m] = (floatx4){0.f, 0.f, 0.f, 0.f};
#pragma unroll
                    for (int g = 0; g < 4; ++g) {
                        const int n = g * 128 + hhj;
                        short8 bf[4];
#pragma unroll
                        for (int k = 0; k < 4; ++k)
                            bf[k] = ld8bf(Wih + (size_t)n * Dd + k * 32 + quad * 8);
#pragma unroll
                        for (int k = 0; k < 4; ++k)
#pragma unroll
                            for (int m = 0; m < 4; ++m)
                                acc[g][m] = MFMA16(af[m][k], bf[k], acc[g][m]);
                    }
                    // pack 4 gates per (b-row) and store 8 B
#pragma unroll
                    for (int m = 0; m < 4; ++m) {
#pragma unroll
                        for (int r = 0; r < 4; ++r) {
                            const int brow = m * 16 + quad * 4 + r;
                            union { unsigned short us[4]; uintx2 u2; } p;
#pragma unroll
                            for (int g = 0; g < 4; ++g)
                                p.us[g] = f2bf(acc[g][m][r] + bias[jj][g]);
                            *reinterpret_cast<uintx2*>(
                                xg + ((size_t)t * Bsz + brow) * Gg + hhj * 4) =
                                p.u2;
                        }
                    }
                }
                __syncthreads();  // staged buf visible; stores drained (vmcnt0)
            }

            // release: all 256 threads' stores are complete (barrier drained)
            if (tid == 0) {
                __builtin_amdgcn_fence(__ATOMIC_RELEASE, "agent");
                __hip_atomic_store(&flags[chunk], SENT, __ATOMIC_RELAXED,
                                   __HIP_MEMORY_SCOPE_AGENT);
            }
        }
    }
}

// ---------------- Fallback (R2 working kernel) if ws too small ---------------
__global__ __launch_bounds__(512, 2) void lstm_fused_fb(
    const int*   __restrict__ tokens,
    const float* __restrict__ emb,
    const float* __restrict__ Wih,
    const float* __restrict__ Whh,
    const float* __restrict__ bih,
    const float* __restrict__ bhh,
    float*       __restrict__ out)
{
    __shared__ unsigned short xbuf[2][16 * XS];
    __shared__ unsigned short hbuf2[2][16 * XS];
    __shared__ float scratch[4 * Gg];

    const int tid  = threadIdx.x;
    const int w    = tid >> 6;
    const int l    = tid & 63;
    const int quad = l >> 4;
    const int cl   = l & 15;
    const int bbase = blockIdx.x * 4;
    const int rr = tid >> 7;
    const int hh = tid & 127;

    short8 wih[4][4], whh[4][4];
    float  bias[4];
#pragma unroll
    for (int q = 0; q < 4; ++q) {
        const int n = q * 128 + w * 16 + cl;
#pragma unroll
        for (int kk = 0; kk < 4; ++kk) {
            const int k0 = kk * 32 + quad * 8;
            wih[q][kk] = ld8bf(Wih + n * Dd + k0);
            whh[q][kk] = ld8bf(Whh + n * Hh + k0);
        }
        bias[q] = bih[n] + bhh[n];
    }

    for (int i = tid; i < 16 * XS; i += 512) {
        xbuf[0][i] = 0; xbuf[1][i] = 0; hbuf2[0][i] = 0; hbuf2[1][i] = 0;
    }

    const bool gact = (tid < 128);
    const int  gr = tid >> 5;
    const int  gp = tid & 31;
    float4 gdataf = {0.f, 0.f, 0.f, 0.f};
    if (gact) {
        const int tok = tokens[(bbase + gr) * T_LEN + 0];
        gdataf = *reinterpret_cast<const float4*>(emb + (size_t)tok * Dd + gp * 4);
    }
    __syncthreads();
    if (gact) *reinterpret_cast<uintx2*>(&xbuf[0][gr * XS + gp * 4]) = f4bf(gdataf);
    if (gact) {
        const int tok = tokens[(bbase + gr) * T_LEN + 1];
        gdataf = *reinterpret_cast<const float4*>(emb + (size_t)tok * Dd + gp * 4);
    }
    __syncthreads();

    const int afrag_el = cl * XS + quad * 8;

    floatx4 acc[4];
#pragma unroll
    for (int q = 0; q < 4; ++q) acc[q] = (floatx4){bias[q], bias[q], bias[q], bias[q]};
    {
        short8 xf[4];
#pragma unroll
        for (int kk = 0; kk < 4; ++kk)
            xf[kk] = *reinterpret_cast<const short8*>(&xbuf[0][afrag_el + kk * 32]);
#pragma unroll
        for (int kk = 0; kk < 4; ++kk)
#pragma unroll
            for (int q = 0; q < 4; ++q)
                acc[q] = MFMA16(xf[kk], wih[q][kk], acc[q]);
    }

    float c_state = 0.0f, h_last = 0.0f;

    for (int t = 0; t < T_LEN; ++t) {
        const int cur = t & 1, nxt = cur ^ 1;
        short8 hf[4];
#pragma unroll
        for (int kk = 0; kk < 4; ++kk)
            hf[kk] = *reinterpret_cast<const short8*>(&hbuf2[cur][afrag_el + kk * 32]);
        if (gact && (t + 1 < T_LEN))
            *reinterpret_cast<uintx2*>(&xbuf[nxt][gr * XS + gp * 4]) = f4bf(gdataf);
        if (gact && (t + 2 < T_LEN)) {
            const int tok = tokens[(bbase + gr) * T_LEN + (t + 2)];
            gdataf = *reinterpret_cast<const float4*>(emb + (size_t)tok * Dd + gp * 4);
        }
#pragma unroll
        for (int kk = 0; kk < 4; ++kk)
#pragma unroll
            for (int q = 0; q < 4; ++q)
                acc[q] = MFMA16(hf[kk], whh[q][kk], acc[q]);
        if (quad == 0) {
#pragma unroll
            for (int q = 0; q < 4; ++q) {
                const int n = q * 128 + w * 16 + cl;
#pragma unroll
                for (int r = 0; r < 4; ++r)
                    scratch[r * Gg + n] = acc[q][r];
            }
        }
        __syncthreads();
#pragma unroll
        for (int q = 0; q < 4; ++q) acc[q] = (floatx4){bias[q], bias[q], bias[q], bias[q]};
        if (t + 1 < T_LEN) {
            short8 xf[4];
#pragma unroll
            for (int kk = 0; kk < 4; ++kk)
                xf[kk] = *reinterpret_cast<const short8*>(&xbuf[nxt][afrag_el + kk * 32]);
#pragma unroll
            for (int kk = 0; kk < 4; ++kk)
#pragma unroll
                for (int q = 0; q < 4; ++q)
                    acc[q] = MFMA16(xf[kk], wih[q][kk], acc[q]);
        }
        {
            const float iv = scratch[rr * Gg + hh];
            const float fv = scratch[rr * Gg + 128 + hh];
            const float gv = scratch[rr * Gg + 256 + hh];
            const float ov = scratch[rr * Gg + 384 + hh];
            const float si = sigmoidf_(iv);
            const float sf = sigmoidf_(fv);
            const float so = sigmoidf_(ov);
            const float tg = tanhf_(gv);
            c_state = sf * c_state + si * tg;
            h_last  = so * tanhf_(c_state);
            hbuf2[nxt][rr * XS + hh] = f2bf(h_last);
        }
        __syncthreads();
    }

    const int ob = (bbase + rr) * Hh + hh;
    out[ob]            = h_last;
    out[Bsz * Hh + ob] = c_state;
}

}  // namespace

extern "C" void kernel_launch(void* const* d_in, const int* in_sizes, int n_in,
                              void* d_out, int out_size, void* d_ws, size_t ws_size,
                              hipStream_t stream) {
    (void)in_sizes; (void)n_in; (void)out_size;
    const int*   tokens = (const int*)d_in[0];
    const float* emb    = (const float*)d_in[1];
    const float* Wih    = (const float*)d_in[2];
    const float* Whh    = (const float*)d_in[3];
    const float* bih    = (const float*)d_in[4];
    const float* bhh    = (const float*)d_in[5];

    const size_t xg_bytes = (size_t)T_LEN * Bsz * Gg * sizeof(unsigned short);  // 134 MB
    const size_t need = xg_bytes + NCHUNK * sizeof(unsigned int);
    if (ws_size >= need) {
        unsigned short* xg    = (unsigned short*)d_ws;
        unsigned int*   flags = (unsigned int*)((char*)d_ws + xg_bytes);
        lstm_fused_all<<<CONS + PROD, 256, 0, stream>>>(
            tokens, emb, Wih, Whh, bih, bhh, xg, flags, (float*)d_out);
    } else {
        lstm_fused_fb<<<16, 512, 0, stream>>>(tokens, emb, Wih, Whh, bih, bhh,
                                              (float*)d_out);
    }
}

// Round 4
// 820.908 us; speedup vs baseline: 1.2207x; 1.2207x over previous
//
#include <hip/hip_runtime.h>
#include <hip/hip_bf16.h>

// LSTM encoder, single fused kernel (producer/consumer).
//   Grid = 256 WGs x 256 thr. WGs 0-63: persistent recurrence, one batch row
//   each. WGs 64-255: xg producers, 8 timesteps per chunk (256 chunks),
//   publishing via agent-scope release flags in d_ws.
// Consumer (R4 = R2 barrier structure + spine trims):
//   4 waves; lane pair splits GATES (gh=0 -> {i,g}, gh=1 -> {f,o}), full K
//   per lane, 64 sdot4 in 8-deep chains. q1 ({g,o}) dots run FIRST so
//   sigma(g1) hides under the q0 dot issue; only sigma(g0)+tanh sit on the
//   spine. Pair-split tail: one DPP swap (A <-> sf); 3 transcendental chains.
//   Quant via magic-add fma(so*127, t2, 1.5*2^23).
//   xg prefetch is STREAMING IN-PLACE: substep s loads next-chunk slot s-1
//   (slot 7 re-loaded after its consume at s==7) -- no xcn copy, -16 VGPR.
//   Hot-loop chunk-flag check is FENCE-FREE (relaxed agent load only): every
//   xg line is first-touched strictly after its flag is observed (verified
//   distance-2 ahead), lines are not shared across consumers (distinct 1KB
//   rows), and the dummy chunk-0 re-reads target data that never changes
//   after flag 0 -- so no stale L1/L2 line can exist. Startup keeps full
//   acquire fences. This removes a per-chunk vmcnt(0)+buffer_inv from the
//   spine. Consumers run at s_setprio(1) to win CU arbitration vs
//   co-resident producers during the production window.
//   One lgkmcnt-only barrier/step; h ping-pong = 256 B LDS.
// Fallback single kernel if ws_size too small.

namespace {

constexpr int T_LEN  = 2048;
constexpr int Bsz    = 64;
constexpr int Dd     = 128;
constexpr int Hh     = 128;
constexpr int Gg     = 512;
constexpr int XS     = 136;    // bf16 LDS row stride (producer A-tile / fallback)
constexpr int NCHUNK = 256;    // 8 timesteps per chunk
constexpr int CONS   = 64;     // consumer WGs (one per batch row)
constexpr int PROD   = 192;    // producer WGs
constexpr unsigned int SENT = 0x5EC7C0DEu;

typedef __attribute__((ext_vector_type(8))) short   short8;
typedef __attribute__((ext_vector_type(4))) float   floatx4;
typedef __attribute__((ext_vector_type(4))) int     intx4;
typedef __attribute__((ext_vector_type(2))) unsigned int uintx2;

#define MFMA16(a, b, c) __builtin_amdgcn_mfma_f32_16x16x32_bf16((a), (b), (c), 0, 0, 0)

#if __has_builtin(__builtin_amdgcn_sdot4)
__device__ __forceinline__ int dot4i8(int a, int b, int c) {
    return __builtin_amdgcn_sdot4(a, b, c, false);
}
#else
__device__ __forceinline__ int dot4i8(int a, int b, int c) {
#pragma unroll
    for (int j = 0; j < 4; ++j)
        c += ((a << (24 - 8 * j)) >> 24) * ((b << (24 - 8 * j)) >> 24);
    return c;
}
#endif

// value from partner lane^1 (quad_perm [1,0,3,2]) -- full-rate VALU
__device__ __forceinline__ int xor1_i(int v) {
    return __builtin_amdgcn_mov_dpp(v, 0xB1, 0xF, 0xF, true);
}

__device__ __forceinline__ float sigmoidf_(float x) {
    return __builtin_amdgcn_rcpf(1.0f + __builtin_amdgcn_exp2f(x * -1.44269504f));
}
__device__ __forceinline__ float tanhf_(float x) {
    return __builtin_fmaf(-2.0f,
        __builtin_amdgcn_rcpf(1.0f + __builtin_amdgcn_exp2f(x * 2.88539008f)), 1.0f);
}
__device__ __forceinline__ unsigned short f2bf(float f) {
    __hip_bfloat16 h = __float2bfloat16(f);  // RNE
    union { __hip_bfloat16 b; unsigned short u; } v; v.b = h; return v.u;
}
__device__ __forceinline__ float fi_(unsigned int u) {
    union { unsigned int u; float f; } v; v.u = u; return v.f;
}
__device__ __forceinline__ int f_as_i(float f) {
    union { float f; int i; } v; v.f = f; return v.i;
}
__device__ __forceinline__ float i_as_f(int i) {
    union { int i; float f; } v; v.i = i; return v.f;
}
__device__ __forceinline__ uintx2 f4bf(const float4 v) {
    union { unsigned short us[4]; uintx2 u2; } p;
    p.us[0] = f2bf(v.x); p.us[1] = f2bf(v.y); p.us[2] = f2bf(v.z); p.us[3] = f2bf(v.w);
    return p.u2;
}
__device__ __forceinline__ short8 ld8bf(const float* p) {
    const float4 a = *reinterpret_cast<const float4*>(p);
    const float4 b = *reinterpret_cast<const float4*>(p + 4);
    short8 s;
    s[0] = (short)f2bf(a.x); s[1] = (short)f2bf(a.y);
    s[2] = (short)f2bf(a.z); s[3] = (short)f2bf(a.w);
    s[4] = (short)f2bf(b.x); s[5] = (short)f2bf(b.y);
    s[6] = (short)f2bf(b.z); s[7] = (short)f2bf(b.w);
    return s;
}
// barrier without the compiler's vmcnt(0) drain: LDS-visibility only
__device__ __forceinline__ void lds_barrier() {
    asm volatile("s_waitcnt lgkmcnt(0)\n\ts_barrier" ::: "memory");
}
// startup-path wait: spin + full acquire fence
__device__ __forceinline__ void wait_chunk(const unsigned int* flags, int k) {
    while (__hip_atomic_load(&flags[k], __ATOMIC_RELAXED,
                             __HIP_MEMORY_SCOPE_AGENT) != SENT)
        __builtin_amdgcn_s_sleep(2);
    __builtin_amdgcn_fence(__ATOMIC_ACQUIRE, "agent");
}
// hot-loop wait: spin only, NO fence (see header comment for the argument)
__device__ __forceinline__ void spin_chunk(const unsigned int* flags, int k) {
    while (__hip_atomic_load(&flags[k], __ATOMIC_RELAXED,
                             __HIP_MEMORY_SCOPE_AGENT) != SENT)
        __builtin_amdgcn_s_sleep(2);
}

// =================== fused producer/consumer kernel ==========================
__global__ __launch_bounds__(256) void lstm_fused_all(
    const int*   __restrict__ tokens,
    const float* __restrict__ emb,
    const float* __restrict__ Wih,
    const float* __restrict__ Whh,
    const float* __restrict__ bih,
    const float* __restrict__ bhh,
    unsigned short* __restrict__ xg,     // [T][64][128][4] bf16, in d_ws
    unsigned int*   __restrict__ flags,  // [NCHUNK], in d_ws after xg
    float*       __restrict__ out)       // [2][64][128] fp32
{
    __shared__ __align__(16) unsigned short albs[2][64 * XS];  // producer A-tile

    const int tid = threadIdx.x;

    if (blockIdx.x < CONS) {
        // ================= CONSUMER: one batch row ===========================
        __builtin_amdgcn_s_setprio(1);   // beat co-resident producers
        signed char (*hbuf)[128] =
            reinterpret_cast<signed char (*)[128]>(&albs[0][0]);  // [2][128]

        const int wv = tid >> 6;          // wave 0..3
        const int l  = tid & 63;
        const int gh = l & 1;             // gate-half: 0 -> {i,g}, 1 -> {f,o}
        const int c  = wv * 32 + (l >> 1);  // hidden column
        const int b  = blockIdx.x;        // batch row

        // per-lane activation constants: gh0 computes tanh via
        // 2*sigmoid(2x)-1; gh1 computes a plain sigmoid.
        const float kf = gh ? 1.0f : 2.0f;     // input scale AND output scale
        const float kb = gh ? 0.0f : -1.0f;    // output offset
        const int   sh = gh ? 0 : 16;          // bf16 unpack shift for xg

        // Whh rows for this lane's two gates {gh, 2+gh}, full K -> i8
        int   wq[2][32];
        float dq[2];
#pragma unroll
        for (int q = 0; q < 2; ++q) {
            const int g = q * 2 + gh;
            const float* wr = Whh + (size_t)(g * 128 + c) * Hh;
            float am = 0.f;
#pragma unroll 8
            for (int k = 0; k < 128; k += 4) {
                const float4 v = *reinterpret_cast<const float4*>(wr + k);
                am = fmaxf(am, fmaxf(fmaxf(fabsf(v.x), fabsf(v.y)),
                                     fmaxf(fabsf(v.z), fabsf(v.w))));
            }
            const float swm = fmaxf(am, 1e-20f);
            dq[q] = swm * (1.0f / (127.0f * 127.0f));
            const float inv = 127.0f / swm;
#pragma unroll
            for (int d = 0; d < 32; ++d) {
                const float4 v = *reinterpret_cast<const float4*>(wr + d * 4);
                const int b0 = (int)__builtin_rintf(v.x * inv);
                const int b1 = (int)__builtin_rintf(v.y * inv);
                const int b2 = (int)__builtin_rintf(v.z * inv);
                const int b3 = (int)__builtin_rintf(v.w * inv);
                wq[q][d] = (b0 & 0xff) | ((b1 & 0xff) << 8) |
                           ((b2 & 0xff) << 16) | ((b3 & 0xff) << 24);
            }
        }

        // h(0) = 0 in regs (buffers always written before read); full K
        intx4 hv[8];
#pragma unroll
        for (int j = 0; j < 8; ++j) hv[j] = (intx4){0, 0, 0, 0};

        const unsigned short* xptr = xg + (size_t)b * Gg + c * 4;
        const size_t xstride = (size_t)Bsz * Gg;

        // startup: verify chunks 0 and 1 (full acquire); load chunk 0
        wait_chunk(flags, 0);
        uintx2 xc[8];
#pragma unroll
        for (int u = 0; u < 8; ++u)
            xc[u] = *reinterpret_cast<const uintx2*>(xptr + (size_t)u * xstride);
        wait_chunk(flags, 1);

        float c_state = 0.0f;
        float h_last  = 0.0f;
        unsigned int fpre = SENT;

        for (int g = 0; g < NCHUNK; ++g) {
            int tn = g + 1;
            if (tn >= NCHUNK) tn = 0;            // dummy re-read of chunk 0
            const size_t tb = (size_t)tn * 8;
#pragma unroll
            for (int s = 0; s < 8; ++s) {
                const uintx2 xv = xc[s];          // consume slot s FIRST

                // streaming in-place prefetch of chunk g+1:
                //   substep s>=1 loads slot s-1; substep 7 also re-loads
                //   slot 7 (just consumed above). ~7-substep use distance.
                if (s >= 1)
                    xc[s - 1] = *reinterpret_cast<const uintx2*>(
                        xptr + (tb + (s - 1)) * xstride);
                if (s == 7)
                    xc[7] = *reinterpret_cast<const uintx2*>(
                        xptr + (tb + 7) * xstride);

                if (s == 2) {
                    // prefetch the distance-2 flag (hide L2 latency)
                    if (g + 2 < NCHUNK)
                        fpre = __hip_atomic_load(&flags[g + 2], __ATOMIC_RELAXED,
                                                 __HIP_MEMORY_SCOPE_AGENT);
                }
                if (s == 4) {
                    // distance-2 flag check; fence-free (see header)
                    if (g + 2 < NCHUNK && fpre != SENT) spin_chunk(flags, g + 2);
                }

                // gate q1 ({g,o}) dots FIRST so sigma(g1) hides under the
                // gate q0 dot issue; q0 ({i,f}) second.
                int b0 = 0, b1 = 0, b2 = 0, b3 = 0;
#pragma unroll
                for (int j = 0; j < 8; ++j) {
                    const intx4 h4 = hv[j];
                    b0 = dot4i8(wq[1][j * 4 + 0], h4[0], b0);
                    b1 = dot4i8(wq[1][j * 4 + 1], h4[1], b1);
                    b2 = dot4i8(wq[1][j * 4 + 2], h4[2], b2);
                    b3 = dot4i8(wq[1][j * 4 + 3], h4[3], b3);
                }
                const int m1 = (b0 + b1) + (b2 + b3);

                const float x1 = fi_((xv.y << sh) & 0xffff0000u);  // g or o
                const float g1 = (float)m1 * dq[1] + x1;
                const float r2 = sigmoidf_(g1 * kf);      // sig(2gv) / so
                const float v2 = __builtin_fmaf(r2, kf, kb);  // tg / so
                const float so127 = v2 * 127.0f;          // gh1: so*127

                int a0 = 0, a1 = 0, a2 = 0, a3 = 0;
#pragma unroll
                for (int j = 0; j < 8; ++j) {
                    const intx4 h4 = hv[j];
                    a0 = dot4i8(wq[0][j * 4 + 0], h4[0], a0);
                    a1 = dot4i8(wq[0][j * 4 + 1], h4[1], a1);
                    a2 = dot4i8(wq[0][j * 4 + 2], h4[2], a2);
                    a3 = dot4i8(wq[0][j * 4 + 3], h4[3], a3);
                }
                const int m0 = (a0 + a1) + (a2 + a3);

                const float x0 = fi_((xv.x << sh) & 0xffff0000u);  // i or f
                const float g0 = (float)m0 * dq[0] + x0;
                const float r1 = sigmoidf_(g0);           // si (gh0) / sf (gh1)
                const float A  = r1 * v2;                 // si*tg / (unused)
                // one DPP swap: gh0 sends A, receives sf; gh1 sends sf, recv A
                const float swv = i_as_f(xor1_i(f_as_i(gh ? r1 : A)));
                const float F   = gh ? r1 : swv;          // sf on both lanes
                const float Ag  = gh ? swv : A;           // si*tg on both lanes
                c_state = __builtin_fmaf(F, c_state, Ag);
                const float t2 = tanhf_(c_state);
                h_last = v2 * t2;                         // valid on gh1: so*t2

                const int nxt = (s & 1) ^ 1;        // buffer parity of t+1
                if (gh == 1) {
                    // fused quant: round(so*127 * t2) via magic-add FMA (RNE)
                    const int q =
                        f_as_i(__builtin_fmaf(so127, t2, 12582912.0f));
                    hbuf[nxt][c] = (signed char)(q & 0xff);
                }
                lds_barrier();  // lgkm-only: h visible, vmem stays in flight
#pragma unroll
                for (int j = 0; j < 8; ++j)
                    hv[j] = *reinterpret_cast<const intx4*>(
                        &hbuf[nxt][j * 16]);
            }
        }

        if (gh == 1) {
            out[b * Hh + c]            = h_last;
            out[Bsz * Hh + b * Hh + c] = c_state;
        }
    } else {
        // ================= PRODUCER: xg chunks of 8 timesteps ================
        const int pid  = blockIdx.x - CONS;
        const int wv   = tid >> 6;
        const int l    = tid & 63;
        const int quad = l >> 4;
        const int cl   = l & 15;
        const int srow = tid >> 2, sseg = tid & 3;   // staging: row, 32-col seg

        // bias for this lane's two hh columns (j = wv*2 + jj)
        float bias[2][4];
#pragma unroll
        for (int jj = 0; jj < 2; ++jj) {
            const int hhj = (wv * 2 + jj) * 16 + cl;
#pragma unroll
            for (int g = 0; g < 4; ++g)
                bias[jj][g] = bih[g * 128 + hhj] + bhh[g * 128 + hhj];
        }

        for (int chunk = pid; chunk < NCHUNK; chunk += PROD) {
            const int t0 = chunk * 8;

            {   // stage t0 into buf 0
                const int tok = tokens[srow * T_LEN + t0];
                const float* src = emb + (size_t)tok * Dd + sseg * 32;
#pragma unroll
                for (int p = 0; p < 4; ++p)
                    *reinterpret_cast<short8*>(
                        &albs[0][srow * XS + sseg * 32 + p * 8]) = ld8bf(src + p * 8);
            }
            __syncthreads();

            for (int tt = 0; tt < 8; ++tt) {
                const int cur = tt & 1, nxt = cur ^ 1;
                if (tt < 7) {   // stage next t
                    const int tok = tokens[srow * T_LEN + t0 + tt + 1];
                    const float* src = emb + (size_t)tok * Dd + sseg * 32;
#pragma unroll
                    for (int p = 0; p < 4; ++p)
                        *reinterpret_cast<short8*>(
                            &albs[nxt][srow * XS + sseg * 32 + p * 8]) =
                            ld8bf(src + p * 8);
                }

                // A-fragments for all 4 m-tiles x 4 k-chunks
                short8 af[4][4];
#pragma unroll
                for (int m = 0; m < 4; ++m)
#pragma unroll
                    for (int k = 0; k < 4; ++k)
                        af[m][k] = *reinterpret_cast<const short8*>(
                            &albs[cur][(m * 16 + cl) * XS + k * 32 + quad * 8]);

                const int t = t0 + tt;
#pragma unroll
                for (int jj = 0; jj < 2; ++jj) {
                    const int hhj = (wv * 2 + jj) * 16 + cl;
                    floatx4 acc[4][4];  // [g][m]
#pragma unroll
                    for (int g = 0; g < 4; ++g)
#pragma unroll
                        for (int m = 0; m < 4; ++m)
                            acc[g][m] = (floatx4){0.f, 0.f, 0.f, 0.f};
#pragma unroll
                    for (int g = 0; g < 4; ++g) {
                        const int n = g * 128 + hhj;
                        short8 bf[4];
#pragma unroll
                        for (int k = 0; k < 4; ++k)
                            bf[k] = ld8bf(Wih + (size_t)n * Dd + k * 32 + quad * 8);
#pragma unroll
                        for (int k = 0; k < 4; ++k)
#pragma unroll
                            for (int m = 0; m < 4; ++m)
                                acc[g][m] = MFMA16(af[m][k], bf[k], acc[g][m]);
                    }
                    // pack 4 gates per (b-row) and store 8 B
#pragma unroll
                    for (int m = 0; m < 4; ++m) {
#pragma unroll
                        for (int r = 0; r < 4; ++r) {
                            const int brow = m * 16 + quad * 4 + r;
                            union { unsigned short us[4]; uintx2 u2; } p;
#pragma unroll
                            for (int g = 0; g < 4; ++g)
                                p.us[g] = f2bf(acc[g][m][r] + bias[jj][g]);
                            *reinterpret_cast<uintx2*>(
                                xg + ((size_t)t * Bsz + brow) * Gg + hhj * 4) =
                                p.u2;
                        }
                    }
                }
                __syncthreads();  // staged buf visible; stores drained (vmcnt0)
            }

            // release: all 256 threads' stores are complete (barrier drained)
            if (tid == 0) {
                __builtin_amdgcn_fence(__ATOMIC_RELEASE, "agent");
                __hip_atomic_store(&flags[chunk], SENT, __ATOMIC_RELAXED,
                                   __HIP_MEMORY_SCOPE_AGENT);
            }
        }
    }
}

// ---------------- Fallback (R2 working kernel) if ws too small ---------------
__global__ __launch_bounds__(512, 2) void lstm_fused_fb(
    const int*   __restrict__ tokens,
    const float* __restrict__ emb,
    const float* __restrict__ Wih,
    const float* __restrict__ Whh,
    const float* __restrict__ bih,
    const float* __restrict__ bhh,
    float*       __restrict__ out)
{
    __shared__ unsigned short xbuf[2][16 * XS];
    __shared__ unsigned short hbuf2[2][16 * XS];
    __shared__ float scratch[4 * Gg];

    const int tid  = threadIdx.x;
    const int w    = tid >> 6;
    const int l    = tid & 63;
    const int quad = l >> 4;
    const int cl   = l & 15;
    const int bbase = blockIdx.x * 4;
    const int rr = tid >> 7;
    const int hh = tid & 127;

    short8 wih[4][4], whh[4][4];
    float  bias[4];
#pragma unroll
    for (int q = 0; q < 4; ++q) {
        const int n = q * 128 + w * 16 + cl;
#pragma unroll
        for (int kk = 0; kk < 4; ++kk) {
            const int k0 = kk * 32 + quad * 8;
            wih[q][kk] = ld8bf(Wih + n * Dd + k0);
            whh[q][kk] = ld8bf(Whh + n * Hh + k0);
        }
        bias[q] = bih[n] + bhh[n];
    }

    for (int i = tid; i < 16 * XS; i += 512) {
        xbuf[0][i] = 0; xbuf[1][i] = 0; hbuf2[0][i] = 0; hbuf2[1][i] = 0;
    }

    const bool gact = (tid < 128);
    const int  gr = tid >> 5;
    const int  gp = tid & 31;
    float4 gdataf = {0.f, 0.f, 0.f, 0.f};
    if (gact) {
        const int tok = tokens[(bbase + gr) * T_LEN + 0];
        gdataf = *reinterpret_cast<const float4*>(emb + (size_t)tok * Dd + gp * 4);
    }
    __syncthreads();
    if (gact) *reinterpret_cast<uintx2*>(&xbuf[0][gr * XS + gp * 4]) = f4bf(gdataf);
    if (gact) {
        const int tok = tokens[(bbase + gr) * T_LEN + 1];
        gdataf = *reinterpret_cast<const float4*>(emb + (size_t)tok * Dd + gp * 4);
    }
    __syncthreads();

    const int afrag_el = cl * XS + quad * 8;

    floatx4 acc[4];
#pragma unroll
    for (int q = 0; q < 4; ++q) acc[q] = (floatx4){bias[q], bias[q], bias[q], bias[q]};
    {
        short8 xf[4];
#pragma unroll
        for (int kk = 0; kk < 4; ++kk)
            xf[kk] = *reinterpret_cast<const short8*>(&xbuf[0][afrag_el + kk * 32]);
#pragma unroll
        for (int kk = 0; kk < 4; ++kk)
#pragma unroll
            for (int q = 0; q < 4; ++q)
                acc[q] = MFMA16(xf[kk], wih[q][kk], acc[q]);
    }

    float c_state = 0.0f, h_last = 0.0f;

    for (int t = 0; t < T_LEN; ++t) {
        const int cur = t & 1, nxt = cur ^ 1;
        short8 hf[4];
#pragma unroll
        for (int kk = 0; kk < 4; ++kk)
            hf[kk] = *reinterpret_cast<const short8*>(&hbuf2[cur][afrag_el + kk * 32]);
        if (gact && (t + 1 < T_LEN))
            *reinterpret_cast<uintx2*>(&xbuf[nxt][gr * XS + gp * 4]) = f4bf(gdataf);
        if (gact && (t + 2 < T_LEN)) {
            const int tok = tokens[(bbase + gr) * T_LEN + (t + 2)];
            gdataf = *reinterpret_cast<const float4*>(emb + (size_t)tok * Dd + gp * 4);
        }
#pragma unroll
        for (int kk = 0; kk < 4; ++kk)
#pragma unroll
            for (int q = 0; q < 4; ++q)
                acc[q] = MFMA16(hf[kk], whh[q][kk], acc[q]);
        if (quad == 0) {
#pragma unroll
            for (int q = 0; q < 4; ++q) {
                const int n = q * 128 + w * 16 + cl;
#pragma unroll
                for (int r = 0; r < 4; ++r)
                    scratch[r * Gg + n] = acc[q][r];
            }
        }
        __syncthreads();
#pragma unroll
        for (int q = 0; q < 4; ++q) acc[q] = (floatx4){bias[q], bias[q], bias[q], bias[q]};
        if (t + 1 < T_LEN) {
            short8 xf[4];
#pragma unroll
            for (int kk = 0; kk < 4; ++kk)
                xf[kk] = *reinterpret_cast<const short8*>(&xbuf[nxt][afrag_el + kk * 32]);
#pragma unroll
            for (int kk = 0; kk < 4; ++kk)
#pragma unroll
                for (int q = 0; q < 4; ++q)
                    acc[q] = MFMA16(xf[kk], wih[q][kk], acc[q]);
        }
        {
            const float iv = scratch[rr * Gg + hh];
            const float fv = scratch[rr * Gg + 128 + hh];
            const float gv = scratch[rr * Gg + 256 + hh];
            const float ov = scratch[rr * Gg + 384 + hh];
            const float si = sigmoidf_(iv);
            const float sf = sigmoidf_(fv);
            const float so = sigmoidf_(ov);
            const float tg = tanhf_(gv);
            c_state = sf * c_state + si * tg;
            h_last  = so * tanhf_(c_state);
            hbuf2[nxt][rr * XS + hh] = f2bf(h_last);
        }
        __syncthreads();
    }

    const int ob = (bbase + rr) * Hh + hh;
    out[ob]            = h_last;
    out[Bsz * Hh + ob] = c_state;
}

}  // namespace

extern "C" void kernel_launch(void* const* d_in, const int* in_sizes, int n_in,
                              void* d_out, int out_size, void* d_ws, size_t ws_size,
                              hipStream_t stream) {
    (void)in_sizes; (void)n_in; (void)out_size;
    const int*   tokens = (const int*)d_in[0];
    const float* emb    = (const float*)d_in[1];
    const float* Wih    = (const float*)d_in[2];
    const float* Whh    = (const float*)d_in[3];
    const float* bih    = (const float*)d_in[4];
    const float* bhh    = (const float*)d_in[5];

    const size_t xg_bytes = (size_t)T_LEN * Bsz * Gg * sizeof(unsigned short);  // 134 MB
    const size_t need = xg_bytes + NCHUNK * sizeof(unsigned int);
    if (ws_size >= need) {
        unsigned short* xg    = (unsigned short*)d_ws;
        unsigned int*   flags = (unsigned int*)((char*)d_ws + xg_bytes);
        lstm_fused_all<<<CONS + PROD, 256, 0, stream>>>(
            tokens, emb, Wih, Whh, bih, bhh, xg, flags, (float*)d_out);
    } else {
        lstm_fused_fb<<<16, 512, 0, stream>>>(tokens, emb, Wih, Whh, bih, bhh,
                                              (float*)d_out);
    }
}